// Round 10
// baseline (104.246 us; speedup 1.0000x reference)
//
#include <hip/hip_runtime.h>

// Receptive-field spike encoder:
//   out[t, b, d] = ( clip( (int)(scaling[d] * |x[b] - center[d]|), 0, T-1 ) == t ) ? 1 : 0
// Output [T, B, N=16] float32, 512 MiB -> write-BW-bound.
//
// Round-10: low-occupancy streaming (fillBuffer's real shape). Body identical
// to round 9; grid changed from 2048 blocks (8/CU, 32 waves/CU) to 256 blocks
// (1/CU, 4 waves/CU), each owning one contiguous 2 MiB chunk. Theory: with 32
// resident waves/CU the CU's outgoing store stream interleaves 32 distinct
// 16 KiB runs, thrashing TCC write-combine / DRAM page locality; fillBuffer
// sustains 6.7+ TB/s at ~3.3 waves/CU. 4 waves x 16 outstanding nt-stores
// still cover store latency. Store path unchanged: nt dwordx4, lane i at
// base + i*16 (1 KiB per wave-instruction), wave-contiguous 16 KiB runs.

typedef float f32x4 __attribute__((ext_vector_type(4)));

#define SUBS  32  // 64 KiB sub-chunks per block -> 2 MiB per block
#define ITERS 16  // 16B chunks per thread per sub-chunk

__global__ void __launch_bounds__(256)
rf_encode_lin(const float* __restrict__ x,
              const float* __restrict__ center,
              const float* __restrict__ scaling,
              float* __restrict__ out,
              int logB, int Bmask, int T) {
    const int lane = threadIdx.x & 63;
    const int wave = threadIdx.x >> 6;
    const int qt   = lane & 3;   // which 4 of the 16 receptive fields

    const f32x4 c4 = reinterpret_cast<const f32x4*>(center)[qt];
    const f32x4 s4 = reinterpret_cast<const f32x4*>(scaling)[qt];

    // block owns 2 MiB = 32768 rows, all within ONE t-plane (B % 32768 == 0)
    const long long blockRow0 = (long long)blockIdx.x << 15;   // * 32768 rows
    const int t       = (int)(blockRow0 >> logB);              // block-uniform
    const int rowBase = (int)(blockRow0 & Bmask);              // first b of block

    for (int s = 0; s < SUBS; ++s) {
        // this sub-chunk: 64 KiB = 1024 rows
        const int subRow0 = rowBase + s * 1024 + wave * 256 + (lane >> 2);

        // preload the 16 x-values for this sub-chunk
        float xv[ITERS];
        #pragma unroll
        for (int it = 0; it < ITERS; ++it)
            xv[it] = x[subRow0 + it * 16];

        // wave owns a contiguous 16 KiB run within the sub-chunk
        f32x4* o = reinterpret_cast<f32x4*>(out)
                 + (((long long)blockIdx.x << 17) + (s << 12) + (wave << 10) + lane);

        #pragma unroll
        for (int it = 0; it < ITERS; ++it) {
            const float xb = xv[it];
            // exact numpy op sequence: sub, abs, mul, trunc-to-int32, clip
            int v0 = (int)(s4.x * fabsf(xb - c4.x)); v0 = min(max(v0, 0), T - 1);
            int v1 = (int)(s4.y * fabsf(xb - c4.y)); v1 = min(max(v1, 0), T - 1);
            int v2 = (int)(s4.z * fabsf(xb - c4.z)); v2 = min(max(v2, 0), T - 1);
            int v3 = (int)(s4.w * fabsf(xb - c4.w)); v3 = min(max(v3, 0), T - 1);
            f32x4 r;
            r.x = (v0 == t) ? 1.0f : 0.0f;
            r.y = (v1 == t) ? 1.0f : 0.0f;
            r.z = (v2 == t) ? 1.0f : 0.0f;
            r.w = (v3 == t) ? 1.0f : 0.0f;
            __builtin_nontemporal_store(r, o + it * 64);
        }
    }
}

// generic fallback (N != 16, B not pow2, or B not divisible by 32768)
__global__ void rf_encode_generic(const float* __restrict__ x,
                                  const float* __restrict__ center,
                                  const float* __restrict__ scaling,
                                  float* __restrict__ out,
                                  int B, int N, int T) {
    long long tid = (long long)blockIdx.x * blockDim.x + threadIdx.x;
    long long total = (long long)T * B;
    if (tid >= total) return;
    int b = (int)(tid % B);
    int t = (int)(tid / B);
    float xb = x[b];
    float* o = out + ((long long)t * B + (long long)b) * N;
    for (int d = 0; d < N; ++d) {
        float dist = fabsf(xb - center[d]);
        int v = (int)(scaling[d] * dist);
        v = min(max(v, 0), T - 1);
        o[d] = (v == t) ? 1.0f : 0.0f;
    }
}

extern "C" void kernel_launch(void* const* d_in, const int* in_sizes, int n_in,
                              void* d_out, int out_size, void* d_ws, size_t ws_size,
                              hipStream_t stream) {
    const float* x       = (const float*)d_in[0];
    const float* center  = (const float*)d_in[1];
    const float* scaling = (const float*)d_in[2];
    float* out = (float*)d_out;

    int B = in_sizes[0];
    int N = in_sizes[1];
    int T = (int)((long long)out_size / ((long long)B * (long long)N));

    bool bpow2 = (B & (B - 1)) == 0;
    long long rows = (long long)T * B;
    if (N == 16 && bpow2 && (B % 32768) == 0 && (rows % 32768) == 0) {
        int logB = 0;
        while ((1 << logB) < B) ++logB;
        int nblocks = (int)(rows >> 15);   // 32768 rows (2 MiB) per block
        rf_encode_lin<<<nblocks, 256, 0, stream>>>(x, center, scaling, out,
                                                   logB, B - 1, T);
    } else {
        const int block = 256;
        int blocks = (int)((rows + block - 1) / block);
        rf_encode_generic<<<blocks, block, 0, stream>>>(x, center, scaling, out, B, N, T);
    }
}

// Round 11
// 98.337 us; speedup vs baseline: 1.0601x; 1.0601x over previous
//
#include <hip/hip_runtime.h>

// Receptive-field spike encoder:
//   out[t, b, d] = ( clip( (int)(scaling[d] * |x[b] - center[d]|), 0, T-1 ) == t ) ? 1 : 0
// Output [T, B, N=16] float32, 512 MiB -> write-BW-bound.
//
// Round-11: round-9 structure (best measured: 2048 blocks x contiguous 256 KiB
// chunks, 100.5 us) with ONE change: plain cached stores instead of
// nontemporal. nt was only ever tested at the old strided layout (null);
// at the dense-linear layout, L2 write-back may aggregate full dirty lines
// into larger DRAM bursts than nt's direct path (fillBuffer, 6.86 TB/s here,
// is a plain-store blit kernel). Everything else identical to round 9:
// lane i stores 16B at base + i*16 (1 KiB per wave-instruction),
// wave-contiguous 16 KiB runs, t hoisted block-uniform, x preloaded.

typedef float f32x4 __attribute__((ext_vector_type(4)));

#define SUBS  4   // 64 KiB sub-chunks per block -> 256 KiB per block
#define ITERS 16  // 16B chunks per thread per sub-chunk

__global__ void __launch_bounds__(256)
rf_encode_lin(const float* __restrict__ x,
              const float* __restrict__ center,
              const float* __restrict__ scaling,
              float* __restrict__ out,
              int logB, int Bmask, int T) {
    const int lane = threadIdx.x & 63;
    const int wave = threadIdx.x >> 6;
    const int qt   = lane & 3;   // which 4 of the 16 receptive fields

    const f32x4 c4 = reinterpret_cast<const f32x4*>(center)[qt];
    const f32x4 s4 = reinterpret_cast<const f32x4*>(scaling)[qt];

    // block owns 256 KiB = 4096 rows, all within ONE t-plane (B % 4096 == 0)
    const long long blockRow0 = (long long)blockIdx.x << 12;   // * 4096 rows
    const int t       = (int)(blockRow0 >> logB);              // block-uniform
    const int rowBase = (int)(blockRow0 & Bmask);              // first b of block

    for (int s = 0; s < SUBS; ++s) {
        // this sub-chunk: 64 KiB = 1024 rows
        const int subRow0 = rowBase + s * 1024 + wave * 256 + (lane >> 2);

        // preload the 16 x-values for this sub-chunk
        float xv[ITERS];
        #pragma unroll
        for (int it = 0; it < ITERS; ++it)
            xv[it] = x[subRow0 + it * 16];

        // wave owns a contiguous 16 KiB run within the sub-chunk
        f32x4* o = reinterpret_cast<f32x4*>(out)
                 + (((long long)blockIdx.x << 14) + (s << 12) + (wave << 10) + lane);

        #pragma unroll
        for (int it = 0; it < ITERS; ++it) {
            const float xb = xv[it];
            // exact numpy op sequence: sub, abs, mul, trunc-to-int32, clip
            int v0 = (int)(s4.x * fabsf(xb - c4.x)); v0 = min(max(v0, 0), T - 1);
            int v1 = (int)(s4.y * fabsf(xb - c4.y)); v1 = min(max(v1, 0), T - 1);
            int v2 = (int)(s4.z * fabsf(xb - c4.z)); v2 = min(max(v2, 0), T - 1);
            int v3 = (int)(s4.w * fabsf(xb - c4.w)); v3 = min(max(v3, 0), T - 1);
            f32x4 r;
            r.x = (v0 == t) ? 1.0f : 0.0f;
            r.y = (v1 == t) ? 1.0f : 0.0f;
            r.z = (v2 == t) ? 1.0f : 0.0f;
            r.w = (v3 == t) ? 1.0f : 0.0f;
            o[it * 64] = r;   // plain cached store (the single A/B variable)
        }
    }
}

// generic fallback (N != 16, B not pow2, or rows not divisible by 4096)
__global__ void rf_encode_generic(const float* __restrict__ x,
                                  const float* __restrict__ center,
                                  const float* __restrict__ scaling,
                                  float* __restrict__ out,
                                  int B, int N, int T) {
    long long tid = (long long)blockIdx.x * blockDim.x + threadIdx.x;
    long long total = (long long)T * B;
    if (tid >= total) return;
    int b = (int)(tid % B);
    int t = (int)(tid / B);
    float xb = x[b];
    float* o = out + ((long long)t * B + (long long)b) * N;
    for (int d = 0; d < N; ++d) {
        float dist = fabsf(xb - center[d]);
        int v = (int)(scaling[d] * dist);
        v = min(max(v, 0), T - 1);
        o[d] = (v == t) ? 1.0f : 0.0f;
    }
}

extern "C" void kernel_launch(void* const* d_in, const int* in_sizes, int n_in,
                              void* d_out, int out_size, void* d_ws, size_t ws_size,
                              hipStream_t stream) {
    const float* x       = (const float*)d_in[0];
    const float* center  = (const float*)d_in[1];
    const float* scaling = (const float*)d_in[2];
    float* out = (float*)d_out;

    int B = in_sizes[0];
    int N = in_sizes[1];
    int T = (int)((long long)out_size / ((long long)B * (long long)N));

    bool bpow2 = (B & (B - 1)) == 0;
    long long rows = (long long)T * B;
    if (N == 16 && bpow2 && (B % 4096) == 0 && (rows % 4096) == 0) {
        int logB = 0;
        while ((1 << logB) < B) ++logB;
        int nblocks = (int)(rows >> 12);   // 4096 rows (256 KiB) per block
        rf_encode_lin<<<nblocks, 256, 0, stream>>>(x, center, scaling, out,
                                                   logB, B - 1, T);
    } else {
        const int block = 256;
        int blocks = (int)((rows + block - 1) / block);
        rf_encode_generic<<<blocks, block, 0, stream>>>(x, center, scaling, out, B, N, T);
    }
}